// Round 9
// baseline (102.568 us; speedup 1.0000x reference)
//
#include <hip/hip_runtime.h>

#define NNODES 50000
#define FT 8
#define DD 64
#define KK 16384
#define CAPF 16          // per-(node,type) bucket = exactly one 64B line
#define OVFCAP 32768     // overflow list capacity (P(hit) ~ 1e-7 per cell)
#define NBW 1568         // bitmask words >= ceil(50000/32)

// ---------------- ws layout (int units) ----------------
// cnt   [0,      400000)   per-(node,type) counts          \
// bits  [400000, 401568)   needed-node bitmask              | zeroed by ONE
// headp [401568, 451568)   node -> k+1 linked list (0=none) | hipMemsetAsync
// gtot  [451568, 451572)   [0]=overflow cursor             /
// nxt   [451572, 467956)   k -> next k+1
// ovf_key [467956, 500724)
// ovf_e   [500724, 533492)
// sorted  [533504, 533504+50000*8*16)  per-(node,type) buckets (25.6MB, 64B-aligned)

__global__ void mark_kernel(const int* __restrict__ core, unsigned* __restrict__ bits,
                            int* __restrict__ headp, int* __restrict__ nxtp) {
    int k = blockIdx.x * 256 + threadIdx.x;
    if (k >= KK) return;
    int node = core[k];
    nxtp[k] = atomicExch(&headp[node], k + 1);   // push k (stored as k+1, 0 = empty)
    atomicOr(&bits[node >> 5], 1u << (node & 31));
}

__global__ void scatter_kernel(const int4* __restrict__ esrc4, const int4* __restrict__ edst4,
                               const int* __restrict__ rawd, const unsigned* __restrict__ bits,
                               int* __restrict__ cnt, int* __restrict__ sorted,
                               int* __restrict__ gtot, int* __restrict__ ovf_key,
                               int* __restrict__ ovf_e, int nE) {
    int t = blockIdx.x * 256 + threadIdx.x;
    int e = t * 8;
    if (e >= nE) return;
    if (e + 7 < nE) {
        int4 sA = esrc4[t * 2], sB = esrc4[t * 2 + 1];
        int4 dA = edst4[t * 2], dB = edst4[t * 2 + 1];
        int sv[8] = {sA.x, sA.y, sA.z, sA.w, sB.x, sB.y, sB.z, sB.w};
        int dv[8] = {dA.x, dA.y, dA.z, dA.w, dB.x, dB.y, dB.z, dB.w};
#pragma unroll
        for (int j = 0; j < 8; ++j) {
            int sn = sv[j];
            if (!((bits[sn >> 5] >> (sn & 31)) & 1u)) continue;
            int cell = sn * FT + rawd[dv[j]];
            int p = atomicAdd(&cnt[cell], 1);
            if (p < CAPF) {
                sorted[(size_t)cell * CAPF + p] = e + j;
            } else {
                int q = atomicAdd(&gtot[0], 1);
                if (q < OVFCAP) { ovf_key[q] = cell; ovf_e[q] = e + j; }
            }
        }
    } else {
        const int* esrc = (const int*)esrc4;
        const int* edst = (const int*)edst4;
        for (; e < nE; ++e) {
            int sn = esrc[e];
            if (!((bits[sn >> 5] >> (sn & 31)) & 1u)) continue;
            int cell = sn * FT + rawd[edst[e]];
            int p = atomicAdd(&cnt[cell], 1);
            if (p < CAPF) {
                sorted[(size_t)cell * CAPF + p] = e;
            } else {
                int q = atomicAdd(&gtot[0], 1);
                if (q < OVFCAP) { ovf_key[q] = cell; ovf_e[q] = e; }
            }
        }
    }
}

#define RL(x) __builtin_amdgcn_readfirstlane(x)

// One wave per node (lane = dim); early-exit on bitmask.
// 3-hop chain: bits/cnt -> bucket ids -> nt row gathers.
__global__ void compute_kernel(const unsigned* __restrict__ bits, const int* __restrict__ cnt,
                               const int* __restrict__ sorted, const int* __restrict__ headp,
                               const int* __restrict__ nxtp, const float* __restrict__ evals,
                               const int* __restrict__ gtot, const int* __restrict__ ovf_key,
                               const int* __restrict__ ovf_e, float* __restrict__ out) {
    int node = (blockIdx.x * blockDim.x + threadIdx.x) >> 6;
    int lane = threadIdx.x & 63;
    if (node >= NNODES) return;
    if (!((bits[node >> 5] >> (node & 31)) & 1u)) return;

    const int4* c4 = (const int4*)(cnt + node * FT);
    int4 cA = c4[0], cB = c4[1];
    int cf[FT] = { RL(cA.x), RL(cA.y), RL(cA.z), RL(cA.w),
                   RL(cB.x), RL(cB.y), RL(cB.z), RL(cB.w) };
    int deg = 0;
    bool anyovf = false;
#pragma unroll
    for (int f = 0; f < FT; ++f) { deg += cf[f]; anyovf |= (cf[f] > CAPF); }

    // all bucket-id loads issued up front (each bucket = one 64B line, always in-bounds)
    const int4* bkt4 = (const int4*)(sorted + (size_t)node * FT * CAPF);
    int4 id0[FT], id1[FT];
#pragma unroll
    for (int f = 0; f < FT; ++f) { id0[f] = bkt4[f * 4]; id1[f] = bkt4[f * 4 + 1]; }

    float rmax[FT];
#pragma unroll
    for (int f = 0; f < FT; ++f) {
        int n = cf[f] < CAPF ? cf[f] : CAPF;
        float m0 = -INFINITY, m1 = -INFINITY, m2 = -INFINITY, m3 = -INFINITY;
        if (n > 0) m0 = __builtin_nontemporal_load(evals + (size_t)RL(id0[f].x) * DD + lane);
        if (n > 1) m1 = __builtin_nontemporal_load(evals + (size_t)RL(id0[f].y) * DD + lane);
        if (n > 2) m2 = __builtin_nontemporal_load(evals + (size_t)RL(id0[f].z) * DD + lane);
        if (n > 3) m3 = __builtin_nontemporal_load(evals + (size_t)RL(id0[f].w) * DD + lane);
        if (n > 4) m0 = fmaxf(m0, __builtin_nontemporal_load(evals + (size_t)RL(id1[f].x) * DD + lane));
        if (n > 5) m1 = fmaxf(m1, __builtin_nontemporal_load(evals + (size_t)RL(id1[f].y) * DD + lane));
        if (n > 6) m2 = fmaxf(m2, __builtin_nontemporal_load(evals + (size_t)RL(id1[f].z) * DD + lane));
        if (n > 7) m3 = fmaxf(m3, __builtin_nontemporal_load(evals + (size_t)RL(id1[f].w) * DD + lane));
        if (n > 8) {   // rare tail (Poisson lambda~4)
            const int* bkt = sorted + ((size_t)node * FT + f) * CAPF;
            for (int i = 8; i < n; ++i)
                m0 = fmaxf(m0, __builtin_nontemporal_load(evals + (size_t)RL(bkt[i]) * DD + lane));
        }
        rmax[f] = fmaxf(fmaxf(m0, m1), fmaxf(m2, m3));
    }

    if (anyovf) {   // cold path: effectively unreachable, kept for correctness
        int no = gtot[0]; if (no > OVFCAP) no = OVFCAP;
        for (int q = 0; q < no; ++q) {
            int key = ovf_key[q];
            if ((key >> 3) != node) continue;
            int fo = key & 7;
            float v = evals[(size_t)ovf_e[q] * DD + lane];
#pragma unroll
            for (int t = 0; t < FT; ++t)
                if (t == fo) rmax[t] = fmaxf(rmax[t], v);
        }
    }

    float res[FT];
#pragma unroll
    for (int f = 0; f < FT; ++f) {
        int matched = cf[f];
        float val;
        if (matched == 0)        val = 0.0f;                 // no matching edge -> 0
        else if (matched < deg)  val = fmaxf(rmax[f], 0.0f); // a masked-to-zero edge exists
        else                     val = rmax[f];              // all edges matched this type
        res[f] = val;
    }

    for (int k1 = headp[node]; k1 > 0; k1 = nxtp[k1 - 1]) {
        float* op = out + (size_t)(k1 - 1) * (FT * DD) + lane;
#pragma unroll
        for (int f = 0; f < FT; ++f)
            __builtin_nontemporal_store(res[f], op + f * DD);   // touch-once: bypass L2
    }
}

extern "C" void kernel_launch(void* const* d_in, const int* in_sizes, int n_in,
                              void* d_out, int out_size, void* d_ws, size_t ws_size,
                              hipStream_t stream) {
    const int*   rawd  = (const int*)d_in[0];
    const int*   esrc  = (const int*)d_in[1];
    const int*   edst  = (const int*)d_in[2];
    const float* evals = (const float*)d_in[3];
    const int*   core  = (const int*)d_in[4];
    int nE = in_sizes[1];

    int* wsi      = (int*)d_ws;
    int* cnt      = wsi;
    unsigned* bits = (unsigned*)(wsi + 400000);
    int* headp    = wsi + 401568;
    int* gtot     = wsi + 451568;
    int* nxtp     = wsi + 451572;
    int* ovf_key  = wsi + 467956;
    int* ovf_e    = wsi + 500724;
    int* sorted   = wsi + 533504;   // 64B aligned

    // one memset zeroes cnt | bits | headp(k+1 encoding) | gtot
    hipMemsetAsync(d_ws, 0, (size_t)451572 * sizeof(int), stream);

    mark_kernel<<<(KK + 255) / 256, 256, 0, stream>>>(core, bits, headp, nxtp);

    int nE8 = (nE + 7) / 8;
    scatter_kernel<<<(nE8 + 255) / 256, 256, 0, stream>>>(
        (const int4*)esrc, (const int4*)edst, rawd, bits, cnt, sorted,
        gtot, ovf_key, ovf_e, nE);

    long long cthreads = (long long)NNODES * 64;
    compute_kernel<<<(int)((cthreads + 255) / 256), 256, 0, stream>>>(
        bits, cnt, sorted, headp, nxtp, evals, gtot, ovf_key, ovf_e, (float*)d_out);
}

// Round 10
// 71.151 us; speedup vs baseline: 1.4415x; 1.4415x over previous
//
#include <hip/hip_runtime.h>

#define NNODES 50000
#define FT 8
#define DD 64
#define KK 16384
#define CAPF 16          // per-(node,type) bucket = exactly one 64B line
#define OVFCAP 32768     // overflow list capacity (P(hit) ~ 1e-7 per cell)
#define NBW 1568         // bitmask words >= ceil(50000/32)

// ---------------- ws layout (int units) ----------------
// cnt       [0,      400000)   per-(node,type) true counts
// bits      [400000, 401568)   needed-node bitmask (6.3 KB)
// head      [401568, 451568)   node -> first k (linked list), -1 = none
// nxt       [451568, 467952)   k -> next k
// slot_node [467952, 484336)   compact slot -> node
// gtot      [484336, 484340)   [0]=overflow cursor, [1]=slot cursor
// ovf_key   [484340, 517108)   overflow (node*8+f)
// ovf_e     [517108, 549876)   overflow edge id
// sorted    [549888, 549888+50000*8*16)  per-(node,type) buckets of edge ids (25.6MB)

__global__ void init_kernel(int* __restrict__ cnt, int* __restrict__ bits,
                            int* __restrict__ head, int* __restrict__ gtot) {
    int i = blockIdx.x * 256 + threadIdx.x;
    if (i < NNODES * FT) cnt[i] = 0;
    if (i < NBW) bits[i] = 0;
    if (i < NNODES) head[i] = -1;
    if (i < 4) gtot[i] = 0;
}

__global__ void mark_kernel(const int* __restrict__ core, int* __restrict__ bits,
                            int* __restrict__ head, int* __restrict__ nxt,
                            int* __restrict__ slot_node, int* __restrict__ gtot) {
    int k = blockIdx.x * 256 + threadIdx.x;
    if (k >= KK) return;
    int node = core[k];
    nxt[k] = atomicExch(&head[node], k);                 // push k onto node's list
    unsigned bit = 1u << (node & 31);
    unsigned old = atomicOr((unsigned*)&bits[node >> 5], bit);
    if (!(old & bit)) {                                  // first toucher owns the slot
        int s = atomicAdd(&gtot[1], 1);
        slot_node[s] = node;
    }
}

__global__ void scatter_kernel(const int4* __restrict__ esrc4, const int4* __restrict__ edst4,
                               const int* __restrict__ rawd, const int* __restrict__ bits,
                               int* __restrict__ cnt, int* __restrict__ sorted,
                               int* __restrict__ gtot, int* __restrict__ ovf_key,
                               int* __restrict__ ovf_e, int nE) {
    int t = blockIdx.x * 256 + threadIdx.x;
    int e = t * 8;
    if (e >= nE) return;
    if (e + 7 < nE) {
        int4 sA = esrc4[t * 2], sB = esrc4[t * 2 + 1];
        int4 dA = edst4[t * 2], dB = edst4[t * 2 + 1];
        int sv[8] = {sA.x, sA.y, sA.z, sA.w, sB.x, sB.y, sB.z, sB.w};
        int dv[8] = {dA.x, dA.y, dA.z, dA.w, dB.x, dB.y, dB.z, dB.w};
#pragma unroll
        for (int j = 0; j < 8; ++j) {
            int sn = sv[j];
            if (!((((unsigned)bits[sn >> 5]) >> (sn & 31)) & 1u)) continue;
            int cell = sn * FT + rawd[dv[j]];
            int p = atomicAdd(&cnt[cell], 1);
            if (p < CAPF) {
                sorted[(size_t)cell * CAPF + p] = e + j;
            } else {
                int q = atomicAdd(&gtot[0], 1);
                if (q < OVFCAP) { ovf_key[q] = cell; ovf_e[q] = e + j; }
            }
        }
    } else {
        const int* esrc = (const int*)esrc4;
        const int* edst = (const int*)edst4;
        for (; e < nE; ++e) {
            int sn = esrc[e];
            if (!((((unsigned)bits[sn >> 5]) >> (sn & 31)) & 1u)) continue;
            int cell = sn * FT + rawd[edst[e]];
            int p = atomicAdd(&cnt[cell], 1);
            if (p < CAPF) {
                sorted[(size_t)cell * CAPF + p] = e;
            } else {
                int q = atomicAdd(&gtot[0], 1);
                if (q < OVFCAP) { ovf_key[q] = cell; ovf_e[q] = e; }
            }
        }
    }
}

#define RL(x) __builtin_amdgcn_readfirstlane(x)

// One wave per compact slot (lane = dim). 3-hop dependency graph:
// counts (2x int4) -> all bucket ids (16x int4, branch-free) -> row gathers.
__global__ void compute_kernel(const int* __restrict__ slot_node, const int* __restrict__ cnt,
                               const int* __restrict__ sorted, const int* __restrict__ head,
                               const int* __restrict__ nxt, const float* __restrict__ evals,
                               const int* __restrict__ gtot, const int* __restrict__ ovf_key,
                               const int* __restrict__ ovf_e, float* __restrict__ out) {
    int wave = (blockIdx.x * blockDim.x + threadIdx.x) >> 6;
    int lane = threadIdx.x & 63;
    if (wave >= gtot[1]) return;
    int node = RL(slot_node[wave]);

    const int4* c4 = (const int4*)(cnt + node * FT);
    int4 cA = c4[0], cB = c4[1];
    int cf[FT] = { RL(cA.x), RL(cA.y), RL(cA.z), RL(cA.w),
                   RL(cB.x), RL(cB.y), RL(cB.z), RL(cB.w) };
    int deg = 0;
    bool anyovf = false;
#pragma unroll
    for (int f = 0; f < FT; ++f) { deg += cf[f]; anyovf |= (cf[f] > CAPF); }

    // issue all bucket-id loads up front (each bucket = one 64B line; always in-bounds)
    const int4* bkt4 = (const int4*)(sorted + (size_t)node * FT * CAPF);
    int4 id0[FT], id1[FT];
#pragma unroll
    for (int f = 0; f < FT; ++f) { id0[f] = bkt4[f * 4]; id1[f] = bkt4[f * 4 + 1]; }

    float rmax[FT];
#pragma unroll
    for (int f = 0; f < FT; ++f) {
        int n = cf[f] < CAPF ? cf[f] : CAPF;
        float m0 = -INFINITY, m1 = -INFINITY, m2 = -INFINITY, m3 = -INFINITY;
        if (n > 0) m0 = evals[(size_t)RL(id0[f].x) * DD + lane];
        if (n > 1) m1 = evals[(size_t)RL(id0[f].y) * DD + lane];
        if (n > 2) m2 = evals[(size_t)RL(id0[f].z) * DD + lane];
        if (n > 3) m3 = evals[(size_t)RL(id0[f].w) * DD + lane];
        if (n > 4) m0 = fmaxf(m0, evals[(size_t)RL(id1[f].x) * DD + lane]);
        if (n > 5) m1 = fmaxf(m1, evals[(size_t)RL(id1[f].y) * DD + lane]);
        if (n > 6) m2 = fmaxf(m2, evals[(size_t)RL(id1[f].z) * DD + lane]);
        if (n > 7) m3 = fmaxf(m3, evals[(size_t)RL(id1[f].w) * DD + lane]);
        if (n > 8) {   // rare tail (Poisson lambda~4)
            const int* bkt = sorted + ((size_t)node * FT + f) * CAPF;
            for (int i = 8; i < n; ++i)
                m0 = fmaxf(m0, evals[(size_t)RL(bkt[i]) * DD + lane]);
        }
        rmax[f] = fmaxf(fmaxf(m0, m1), fmaxf(m2, m3));
    }

    if (anyovf) {   // cold path: effectively unreachable, kept for correctness
        int no = gtot[0]; if (no > OVFCAP) no = OVFCAP;
        for (int q = 0; q < no; ++q) {
            int key = ovf_key[q];
            if ((key >> 3) != node) continue;
            int fo = key & 7;
            float v = evals[(size_t)ovf_e[q] * DD + lane];
#pragma unroll
            for (int t = 0; t < FT; ++t)
                if (t == fo) rmax[t] = fmaxf(rmax[t], v);
        }
    }

    float res[FT];
#pragma unroll
    for (int f = 0; f < FT; ++f) {
        int matched = cf[f];
        float val;
        if (matched == 0)        val = 0.0f;                 // no matching edge -> 0
        else if (matched < deg)  val = fmaxf(rmax[f], 0.0f); // a masked-to-zero edge exists
        else                     val = rmax[f];              // all edges matched this type
        res[f] = val;
    }

    for (int k = head[node]; k >= 0; k = nxt[k]) {
        float* op = out + (size_t)k * (FT * DD) + lane;
#pragma unroll
        for (int f = 0; f < FT; ++f) op[f * DD] = res[f];
    }
}

extern "C" void kernel_launch(void* const* d_in, const int* in_sizes, int n_in,
                              void* d_out, int out_size, void* d_ws, size_t ws_size,
                              hipStream_t stream) {
    const int*   rawd  = (const int*)d_in[0];
    const int*   esrc  = (const int*)d_in[1];
    const int*   edst  = (const int*)d_in[2];
    const float* evals = (const float*)d_in[3];
    const int*   core  = (const int*)d_in[4];
    int nE = in_sizes[1];

    int* wsi       = (int*)d_ws;
    int* cnt       = wsi;
    int* bits      = wsi + 400000;
    int* head      = wsi + 401568;
    int* nxt       = wsi + 451568;
    int* slot_node = wsi + 467952;
    int* gtot      = wsi + 484336;
    int* ovf_key   = wsi + 484340;
    int* ovf_e     = wsi + 517108;
    int* sorted    = wsi + 549888;   // byte offset 2199552: 512B aligned

    init_kernel<<<(NNODES * FT + 255) / 256, 256, 0, stream>>>(cnt, bits, head, gtot);
    mark_kernel<<<(KK + 255) / 256, 256, 0, stream>>>(core, bits, head, nxt, slot_node, gtot);

    int nE8 = (nE + 7) / 8;
    scatter_kernel<<<(nE8 + 255) / 256, 256, 0, stream>>>(
        (const int4*)esrc, (const int4*)edst, rawd, bits, cnt, sorted,
        gtot, ovf_key, ovf_e, nE);

    long long cthreads = (long long)KK * 64;   // one wave per slot, upper bound
    compute_kernel<<<(int)((cthreads + 255) / 256), 256, 0, stream>>>(
        slot_node, cnt, sorted, head, nxt, evals, gtot, ovf_key, ovf_e, (float*)d_out);
}